// Round 11
// baseline (250.553 us; speedup 1.0000x reference)
//
#include <hip/hip_runtime.h>
#include <cmath>

// B=16, N=1024, D=512, HEAD=256.  BN = 16384 rows.
#define BN   16384
#define DD   512
#define HEADN 256

typedef unsigned short ushort;
typedef short short8 __attribute__((ext_vector_type(8)));
typedef float floatx4 __attribute__((ext_vector_type(4)));
typedef unsigned short ushort4v __attribute__((ext_vector_type(4)));
typedef unsigned short ushort8v __attribute__((ext_vector_type(8)));

__device__ __forceinline__ ushort f2bf(float v) {
    unsigned int u = __float_as_uint(v);
    unsigned int r = u + 0x7FFFu + ((u >> 16) & 1u);
    return (ushort)(r >> 16);
}
__device__ __forceinline__ float bf2f(ushort u) {
    return __uint_as_float(((unsigned int)u) << 16);
}
// fast tanh: (e^2x - 1)/(e^2x + 1); err ~1e-6 << bf16 ulp
__device__ __forceinline__ float tanh_fast(float x) {
    float xc = fminf(fmaxf(x, -15.0f), 15.0f);
    float e = __expf(2.0f * xc);
    return (e - 1.0f) * __builtin_amdgcn_rcpf(e + 1.0f);
}

// ---------------------------------------------------------------------------
// bf16 MFMA GEMM, tile TM x TN, block-K = BK, 256 threads = 4 waves (2x2).
// Ping-pong LDS, ONE barrier per iter; K-loop fully unrolled (KK template).
// XOR chunk swizzle slot(row,c) = c ^ ((row>>1)&(CPR-1)): ds_read 2-way = free.
// XCD band swizzle: band g&7 owns a contiguous M strip (A stays in its L2).
// Epilogues:
//  EPI 0: fp32 store acc + bias[c]                      -> (float*)Cout, ldc
//  EPI 1: bf16 store tanh_fast(acc + bias[c])           -> (ushort*)Cout, ldc
//  EPI 2: den = 2 - a[r]*f[r]/H[b] computed ON THE FLY (no denom array);
//         u = relu((acc + 2*bias[c]) * rcp(den));
//         if Cout: bf16 store u; if gout: gout[r*512+xoff+c]=bf16(u+xgb[...])
//  EPI 3: s_arr[r] += sum_c acc[r][c] * tcb[r*tcld+c]   (no store)
// ---------------------------------------------------------------------------
template <int TM, int TN, int BK, int KK, int EPI>
__global__ __launch_bounds__(256) void gemm_lds(
    const ushort* __restrict__ A, int lda,
    const ushort* __restrict__ Bt, int N,
    const float* __restrict__ bias,
    const float* __restrict__ af_arr, const float* __restrict__ f_arr,
    const float* __restrict__ Hb_arr,
    const ushort* __restrict__ tcb, int tcld,
    float* __restrict__ s_arr,
    void* __restrict__ Cout, int ldc,
    const ushort* __restrict__ xgb, int xoff, ushort* __restrict__ gout)
{
    constexpr int MI = TM / 32;                 // mfma m-tiles per wave (2x2 grid)
    constexpr int NI = TN / 32;
    constexpr int KSTEPS = BK / 32;
    constexpr int ROWS = TM + TN;
    constexpr int CPR = BK / 8;                 // 16B chunks per row
    constexpr int CPT = (ROWS * CPR) / 256;     // chunks per thread per iter
    constexpr int MT = 16384 / TM;
    constexpr int MT_PER_BAND = MT / 8;
    constexpr int NK = KK / BK;
    __shared__ ushort S[2 * ROWS * BK];

    const int g = blockIdx.x;
    const int band = g & 7, within = g >> 3;
    const int nt = within / MT_PER_BAND;
    const int mt = band * MT_PER_BAND + (within - nt * MT_PER_BAND);
    const int m0 = mt * TM, n0 = nt * TN;
    const int w = threadIdx.x >> 6, L = threadIdx.x & 63;
    const int wr0 = (w >> 1) * (MI * 16);
    const int wc0 = (w & 1) * (NI * 16);
    const int lrow = L & 15, quad = L >> 4;

    // per-thread staging base pointers (computed once; loop adds imm offsets)
    const ushort* gbase[CPT];
#pragma unroll
    for (int rr = 0; rr < CPT; ++rr) {
        const int chunk = rr * 256 + (w << 6) + L;
        const int row = chunk / CPR, slot = chunk % CPR;
        const int ca = slot ^ ((row >> 1) & (CPR - 1));      // swizzled source
        gbase[rr] = (row < TM)
            ? A  + (size_t)(m0 + row) * lda    + (ca << 3)
            : Bt + (size_t)(n0 + row - TM) * KK + (ca << 3);
    }

    floatx4 zero4 = {0.0f, 0.0f, 0.0f, 0.0f};
    floatx4 acc[MI][NI];
#pragma unroll
    for (int i = 0; i < MI; ++i)
#pragma unroll
        for (int j = 0; j < NI; ++j) acc[i][j] = zero4;

    auto stage = [&](int buf, int k0) {
        ushort* Sd = S + buf * (ROWS * BK);
#pragma unroll
        for (int rr = 0; rr < CPT; ++rr) {
            __builtin_amdgcn_global_load_lds(
                (const __attribute__((address_space(1))) unsigned int*)(gbase[rr] + k0),
                (__attribute__((address_space(3))) unsigned int*)(Sd + (rr * 256 + (w << 6)) * 8),
                16, 0, 0);
        }
    };

    stage(0, 0);                                  // preload tile 0
#pragma unroll
    for (int kk = 0; kk < NK; ++kk) {
        __syncthreads();                          // tile kk landed
        if (kk + 1 < NK) stage((kk + 1) & 1, (kk + 1) * BK);  // compile-time guard

        const ushort* Sc = S + (kk & 1) * (ROWS * BK);
        short8 af[KSTEPS][MI], bfr[KSTEPS][NI];
#pragma unroll
        for (int ks = 0; ks < KSTEPS; ++ks) {
#pragma unroll
            for (int mi = 0; mi < MI; ++mi) {
                const int row = wr0 + (mi << 4) + lrow;
                const int slot = ((ks << 2) + quad) ^ ((row >> 1) & (CPR - 1));
                af[ks][mi] = *(const short8*)(Sc + row * BK + (slot << 3));
            }
#pragma unroll
            for (int ni = 0; ni < NI; ++ni) {
                const int row = TM + wc0 + (ni << 4) + lrow;
                const int slot = ((ks << 2) + quad) ^ ((row >> 1) & (CPR - 1));
                bfr[ks][ni] = *(const short8*)(Sc + row * BK + (slot << 3));
            }
        }
#pragma unroll
        for (int ks = 0; ks < KSTEPS; ++ks)
#pragma unroll
            for (int mi = 0; mi < MI; ++mi)
#pragma unroll
                for (int ni = 0; ni < NI; ++ni)
                    acc[mi][ni] = __builtin_amdgcn_mfma_f32_16x16x32_bf16(
                        af[ks][mi], bfr[ks][ni], acc[mi][ni], 0, 0, 0);
    }

    // C/D layout (m89-verified): col = lane&15, row = (lane>>4)*4 + reg.
    if constexpr (EPI == 3) {
#pragma unroll
        for (int mi = 0; mi < MI; ++mi) {
            float rs[4] = {0.f, 0.f, 0.f, 0.f};
#pragma unroll
            for (int ni = 0; ni < NI; ++ni) {
                const int gc = n0 + wc0 + (ni << 4) + lrow;
#pragma unroll
                for (int p = 0; p < 4; ++p) {
                    const int gr = m0 + wr0 + (mi << 4) + (quad << 2) + p;
                    rs[p] += acc[mi][ni][p] * bf2f(tcb[(size_t)gr * tcld + gc]);
                }
            }
#pragma unroll
            for (int p = 0; p < 4; ++p)
#pragma unroll
                for (int o = 1; o < 16; o <<= 1) rs[p] += __shfl_xor(rs[p], o);
            if (lrow == 0) {
#pragma unroll
                for (int p = 0; p < 4; ++p)
                    atomicAdd(s_arr + m0 + wr0 + (mi << 4) + (quad << 2) + p, rs[p]);
            }
        }
    } else {
#pragma unroll
        for (int mi = 0; mi < MI; ++mi) {
#pragma unroll
            for (int p = 0; p < 4; ++p) {
                const int gr = m0 + wr0 + (mi << 4) + (quad << 2) + p;
                float rdv = 1.0f;
                if constexpr (EPI == 2) {
                    const float dv = 2.0f - af_arr[gr] * f_arr[gr]
                                     * __builtin_amdgcn_rcpf(Hb_arr[gr >> 10]);
                    rdv = __builtin_amdgcn_rcpf(dv);
                }
#pragma unroll
                for (int ni = 0; ni < NI; ++ni) {
                    const int gc = n0 + wc0 + (ni << 4) + lrow;
                    const float v = acc[mi][ni][p];
                    if constexpr (EPI == 0) {
                        ((float*)Cout)[(size_t)gr * ldc + gc] = v + bias[gc];
                    } else if constexpr (EPI == 1) {
                        ((ushort*)Cout)[(size_t)gr * ldc + gc] = f2bf(tanh_fast(v + bias[gc]));
                    } else {
                        float u = (v + 2.0f * bias[gc]) * rdv;
                        u = u > 0.0f ? u : 0.0f;
                        if (Cout)
                            ((ushort*)Cout)[(size_t)gr * ldc + gc] = f2bf(u);
                        if (gout)
                            gout[(size_t)gr * 512 + xoff + gc] =
                                f2bf(u + bf2f(xgb[(size_t)gr * 512 + xoff + gc]));
                    }
                }
            }
        }
    }
}

// ---------------------------------------------------------------------------
// Prep: blocks [0,4096): xb = bf16(x) + fdot[r] = x[r].fiw  (one wave/row)
//       blocks [4096,5440): weight transposes fp32[K][N] -> bf16[N][K]
//       block 5440: bias concat
//       blocks [5441,5457): zero the stats region (replaces hipMemsetAsync)
// ---------------------------------------------------------------------------
__global__ __launch_bounds__(256) void prep_k(
    const float* __restrict__ x, const float* __restrict__ fiw,
    ushort* __restrict__ xb, float* __restrict__ fdot,
    const float* __restrict__ tp_w, const float* __restrict__ tc_w,
    const float* __restrict__ bilw, const float* __restrict__ ow,
    const float* __restrict__ w0, const float* __restrict__ w1,
    const float* __restrict__ tp_b, const float* __restrict__ tc_b,
    ushort* __restrict__ tptcwT, ushort* __restrict__ bilwT,
    ushort* __restrict__ owT, ushort* __restrict__ w0T,
    ushort* __restrict__ w1T, float* __restrict__ bias2,
    float* __restrict__ zstats, int zcount)
{
    const int blk0 = blockIdx.x;
    if (blk0 < 4096) {
        const int wv = threadIdx.x >> 6, L = threadIdx.x & 63;
        const int r = (blk0 << 2) + wv;
        const float* xr = x + (size_t)r * DD;
        const int c0 = L << 3;
        float4 v0 = *(const float4*)(xr + c0);
        float4 v1 = *(const float4*)(xr + c0 + 4);
        float4 f0 = *(const float4*)(fiw + c0);
        float4 f1 = *(const float4*)(fiw + c0 + 4);
        float d = v0.x * f0.x + v0.y * f0.y + v0.z * f0.z + v0.w * f0.w
                + v1.x * f1.x + v1.y * f1.y + v1.z * f1.z + v1.w * f1.w;
        ushort8v o;
        o[0] = f2bf(v0.x); o[1] = f2bf(v0.y); o[2] = f2bf(v0.z); o[3] = f2bf(v0.w);
        o[4] = f2bf(v1.x); o[5] = f2bf(v1.y); o[6] = f2bf(v1.z); o[7] = f2bf(v1.w);
        *(ushort8v*)(xb + (size_t)r * DD + c0) = o;
#pragma unroll
        for (int off = 32; off > 0; off >>= 1) d += __shfl_xor(d, off);
        if (L == 0) fdot[r] = d;
        return;
    }
    if (blk0 >= 5441) {                       // zero stats region
        for (int i = (blk0 - 5441) * 256 + threadIdx.x; i < zcount; i += 16 * 256)
            zstats[i] = 0.0f;
        return;
    }
    const int blk = blk0 - 4096;
    if (blk >= 1344) {
        for (int i = threadIdx.x; i < 512; i += 256) {
            bias2[i] = tp_b[i];
            bias2[512 + i] = tc_b[i];
        }
        return;
    }
    const float* W; ushort* Wt; int K, N, local;
    if (blk < 256)       { W = tp_w; Wt = tptcwT;              K = 512; N = 512; local = blk; }
    else if (blk < 512)  { W = tc_w; Wt = tptcwT + 512 * 512;  K = 512; N = 512; local = blk - 256; }
    else if (blk < 768)  { W = bilw; Wt = bilwT;               K = 512; N = 512; local = blk - 512; }
    else if (blk < 1024) { W = ow;   Wt = owT;                 K = 512; N = 512; local = blk - 768; }
    else if (blk < 1152) { W = w0;   Wt = w0T;                 K = 512; N = 256; local = blk - 1024; }
    else                 { W = w1;   Wt = w1T;                 K = 768; N = 256; local = blk - 1152; }

    __shared__ float t[32][33];
    const int nb = N >> 5;
    const int kb = local / nb, nbb = local % nb;
    const int k0 = kb << 5, n0 = nbb << 5;
    const int c = threadIdx.x & 31, r = threadIdx.x >> 5;   // r 0..7
#pragma unroll
    for (int i = 0; i < 4; ++i)
        t[r + 8 * i][c] = W[(size_t)(k0 + r + 8 * i) * N + n0 + c];
    __syncthreads();
#pragma unroll
    for (int i = 0; i < 4; ++i)
        Wt[(size_t)(n0 + r + 8 * i) * K + k0 + c] = f2bf(t[c][r + 8 * i]);
}

// ---------------------------------------------------------------------------
// Per batch: P[c] = sum_n a_n V[n,c]; Q[c] = sum_n a_n f_n V[n,c].  V is bf16.
// grid = 16 batches x 16 row-chunks(64); LDS-reduce then <=16-collider atomics.
// COMPUTE_AF=1 (layer 0): derive a=exp(s_arr), f=exp(fdot) on the fly, write
// a[],f[] (unique row ownership), atomic-accumulate Sb,Hb — replaces the old
// 16-block finalize_k on the critical path.
// ---------------------------------------------------------------------------
template <int COMPUTE_AF>
__global__ __launch_bounds__(256) void batch_pq(
    const ushort* __restrict__ V,
    const float* __restrict__ s_arr, const float* __restrict__ fdot,
    float* __restrict__ a, float* __restrict__ f,
    float* __restrict__ Sb, float* __restrict__ Hb,
    float* __restrict__ P, float* __restrict__ Q, int C)
{
    __shared__ float redP[256][4];
    __shared__ float redQ[256][4];
    const int b = blockIdx.x >> 4;
    const int chunk = blockIdx.x & 15;
    const int c4cnt = C >> 2;
    const int rg = 256 / c4cnt;
    const int c4 = threadIdx.x & (c4cnt - 1);
    const int sub = threadIdx.x / c4cnt;
    const ushort* Vb = V + (size_t)b * 1024 * C;
    const int n0 = chunk << 6;
    float4 p = {0, 0, 0, 0}, q = {0, 0, 0, 0};
    float sS = 0.0f, sH = 0.0f;
    for (int n = n0 + sub; n < n0 + 64; n += rg) {
        const int gn = (b << 10) + n;
        float av, fv;
        if (COMPUTE_AF) {
            av = __expf(s_arr[gn]); fv = __expf(fdot[gn]);
            if (c4 == 0) { a[gn] = av; f[gn] = fv; }
            sS += av; sH += av * fv;
        } else {
            av = a[gn]; fv = f[gn];
        }
        const float afv = av * fv;
        ushort4v u = *(const ushort4v*)(Vb + (size_t)n * C + (c4 << 2));
        float4 v = {bf2f(u[0]), bf2f(u[1]), bf2f(u[2]), bf2f(u[3])};
        p.x += av * v.x; p.y += av * v.y; p.z += av * v.z; p.w += av * v.w;
        q.x += afv * v.x; q.y += afv * v.y; q.z += afv * v.z; q.w += afv * v.w;
    }
    if (COMPUTE_AF && c4 == 0) {
        atomicAdd(Sb + b, sS);
        atomicAdd(Hb + b, sH);
    }
    redP[threadIdx.x][0] = p.x; redP[threadIdx.x][1] = p.y;
    redP[threadIdx.x][2] = p.z; redP[threadIdx.x][3] = p.w;
    redQ[threadIdx.x][0] = q.x; redQ[threadIdx.x][1] = q.y;
    redQ[threadIdx.x][2] = q.z; redQ[threadIdx.x][3] = q.w;
    __syncthreads();
    if (sub == 0) {
        for (int s = 1; s < rg; ++s) {
            const int t2 = threadIdx.x + s * c4cnt;
            p.x += redP[t2][0]; p.y += redP[t2][1]; p.z += redP[t2][2]; p.w += redP[t2][3];
            q.x += redQ[t2][0]; q.y += redQ[t2][1]; q.z += redQ[t2][2]; q.w += redQ[t2][3];
        }
        float* Pp = P + b * C + (c4 << 2);
        float* Qp = Q + b * C + (c4 << 2);
        atomicAdd(Pp + 0, p.x); atomicAdd(Pp + 1, p.y);
        atomicAdd(Pp + 2, p.z); atomicAdd(Pp + 3, p.w);
        atomicAdd(Qp + 0, q.x); atomicAdd(Qp + 1, q.y);
        atomicAdd(Qp + 2, q.z); atomicAdd(Qp + 3, q.w);
    }
}

// ---------------------------------------------------------------------------
// h = adj@V + V (rank-3 + diagonal closed form), V bf16, bf16 store to
// outb[r][co..co+C) with row stride ldo.
// ---------------------------------------------------------------------------
__global__ __launch_bounds__(256) void mix_k(
    const ushort* __restrict__ V, const float* __restrict__ P, const float* __restrict__ Q,
    const float* __restrict__ a, const float* __restrict__ f,
    const float* __restrict__ Sb, const float* __restrict__ Hb,
    ushort* __restrict__ outb, int C, int ldo, int co)
{
    const int idx = blockIdx.x * 256 + threadIdx.x;
    const int c4c = C >> 2;
    const int r = idx / c4c, c4 = idx - r * c4c;
    const int b = r >> 10;
    const float av = a[r], fv = f[r], S = Sb[b], H = Hb[b];
    const float rS = __builtin_amdgcn_rcpf(S);
    const float beta = av * rS * __builtin_amdgcn_rcpf(H);
    const float alpha = 1.0f - av * rS;
    const float cp = rS - beta * fv;
    ushort4v u = *(const ushort4v*)(V + (size_t)r * C + (c4 << 2));
    float4 v = {bf2f(u[0]), bf2f(u[1]), bf2f(u[2]), bf2f(u[3])};
    const float* Pp = P + b * C + (c4 << 2);
    const float* Qp = Q + b * C + (c4 << 2);
    ushort4v o;
    o[0] = f2bf(alpha * v.x + cp * Pp[0] + beta * Qp[0]);
    o[1] = f2bf(alpha * v.y + cp * Pp[1] + beta * Qp[1]);
    o[2] = f2bf(alpha * v.z + cp * Pp[2] + beta * Qp[2]);
    o[3] = f2bf(alpha * v.w + cp * Pp[3] + beta * Qp[3]);
    *(ushort4v*)(outb + (size_t)r * ldo + co + (c4 << 2)) = o;
}

extern "C" void kernel_launch(void* const* d_in, const int* in_sizes, int n_in,
                              void* d_out, int out_size, void* d_ws, size_t ws_size,
                              hipStream_t stream)
{
    (void)in_sizes; (void)n_in; (void)out_size; (void)ws_size;
    const float* x    = (const float*)d_in[0];
    const float* tp_w = (const float*)d_in[1];
    const float* tp_b = (const float*)d_in[2];
    const float* tc_w = (const float*)d_in[3];
    const float* tc_b = (const float*)d_in[4];
    const float* fi_w = (const float*)d_in[5];
    const float* bilw = (const float*)d_in[6];
    const float* w0   = (const float*)d_in[7];
    const float* b0   = (const float*)d_in[8];
    const float* w1   = (const float*)d_in[9];
    const float* b1   = (const float*)d_in[10];
    const float* ow   = (const float*)d_in[11];
    const float* ob   = (const float*)d_in[12];

    char* W = (char*)d_ws;
    ushort* xb    = (ushort*)W;                          // [0,16M)  xb -> gcnb (elem-wise overwrite)
    ushort* gcnb  = xb;
    ushort* tptcb = (ushort*)(W + ((size_t)16 << 20));   // [16M,48M) 32MB; dies after s-GEMM
    ushort* Hbuf  = tptcb;                               // [16M,40M) 24MB overlay: [h0|hg] ld 768
    ushort* g0b   = (ushort*)(W + ((size_t)48 << 20));   // 8MB
    ushort* tptcwT= (ushort*)(W + ((size_t)56 << 20));   // 1024x512
    ushort* bilwT = tptcwT + 524288;                     // 512x512
    ushort* owT   = bilwT + 262144;                      // 512x512
    ushort* w0T   = owT + 262144;                        // 256x512
    ushort* w1T   = w0T + 131072;                        // 256x768
    float*  bias2 = (float*)(w1T + 196608);              // 1024
    float* stats  = (float*)(W + ((size_t)60 << 20));
    // contiguous zero region (zeroed by prep_k): s_arr..Hb = 40992 floats
    float* s_arr  = stats;             // 16384
    float* P0     = s_arr + 16384;     // 8192
    float* Q0     = P0 + 8192;         // 8192
    float* P1     = Q0 + 8192;         // 4096
    float* Q1     = P1 + 4096;         // 4096
    float* Sb     = Q1 + 4096;         // 16
    float* Hb     = Sb + 16;           // 16
    const int zcount = 16384 + 2 * 8192 + 2 * 4096 + 32;
    float* fdot   = Hb + 16;
    float* arr_a  = fdot + BN;
    float* arr_f  = arr_a + BN;

    // prep: xb=bf16(x), fdot, weight transposes, bias concat, stats zeroing
    prep_k<<<5457, 256, 0, stream>>>(x, fi_w, xb, fdot, tp_w, tc_w, bilw, ow, w0, w1,
                                     tp_b, tc_b, tptcwT, bilwT, owT, w0T, w1T, bias2,
                                     s_arr, zcount);
    // [tp|tc] = tanh(x@[tpw|tcw] + [tpb|tcb])  (one N=1024 GEMM, bf16 out)
    gemm_lds<128, 128, 32, 512, 1><<<1024, 256, 0, stream>>>(xb, 512, tptcwT, 1024, bias2,
        nullptr, nullptr, nullptr, nullptr, 0, nullptr, tptcb, 1024, nullptr, 0, nullptr);
    // s[r] = (tp@bilw)[r] . tc[r]   (U never materialized)
    gemm_lds<64, 64, 64, 512, 3><<<2048, 256, 0, stream>>>(tptcb, 1024, bilwT, 512, nullptr,
        nullptr, nullptr, nullptr, tptcb + 512, 1024, s_arr, nullptr, 0, nullptr, 0, nullptr);
    // layer 0: a,f,S,H fused into pq0; h0 = adj@x + x -> Hbuf[:,0:512] bf16
    batch_pq<1><<<256, 256, 0, stream>>>(xb, s_arr, fdot, arr_a, arr_f, Sb, Hb, P0, Q0, 512);
    mix_k<<<8192, 256, 0, stream>>>(xb, P0, Q0, arr_a, arr_f, Sb, Hb, Hbuf, 512, 768, 0);
    // g0 = relu((h0@W0 + 2 b0)/den): store g0b bf16 AND gcn[:,0:256]=bf16(g0+x)
    gemm_lds<64, 64, 64, 512, 2><<<1024, 256, 0, stream>>>(Hbuf, 768, w0T, 256, b0,
        arr_a, arr_f, Hb, nullptr, 0, nullptr, g0b, 256, xb, 0, gcnb);
    // layer 1: hg = adj@g0 + g0 -> Hbuf[:, 512:768] bf16
    batch_pq<0><<<256, 256, 0, stream>>>(g0b, nullptr, nullptr, arr_a, arr_f, nullptr, nullptr, P1, Q1, 256);
    mix_k<<<4096, 256, 0, stream>>>(g0b, P1, Q1, arr_a, arr_f, Sb, Hb, Hbuf, 256, 768, 512);
    // g1 = relu(([h0|hg]@W1 + 2 b1)/den): gcn[:,256:512]=bf16(g1+x) (no g1 buf)
    gemm_lds<64, 64, 64, 768, 2><<<1024, 256, 0, stream>>>(Hbuf, 768, w1T, 256, b1,
        arr_a, arr_f, Hb, nullptr, 0, nullptr, nullptr, 0, xb, 256, gcnb);
    // out = gcn@out_w + out_b  (fp32)
    gemm_lds<64, 64, 64, 512, 0><<<2048, 256, 0, stream>>>(gcnb, 512, owT, 512, ob,
        nullptr, nullptr, nullptr, nullptr, 0, nullptr, (float*)d_out, 512, nullptr, 0, nullptr);
}

// Round 12
// 234.689 us; speedup vs baseline: 1.0676x; 1.0676x over previous
//
#include <hip/hip_runtime.h>
#include <cmath>

// B=16, N=1024, D=512, HEAD=256.  BN = 16384 rows.
#define BN   16384
#define DD   512
#define HEADN 256

typedef unsigned short ushort;
typedef short short8 __attribute__((ext_vector_type(8)));
typedef float floatx4 __attribute__((ext_vector_type(4)));
typedef unsigned short ushort4v __attribute__((ext_vector_type(4)));
typedef unsigned short ushort8v __attribute__((ext_vector_type(8)));

__device__ __forceinline__ ushort f2bf(float v) {
    unsigned int u = __float_as_uint(v);
    unsigned int r = u + 0x7FFFu + ((u >> 16) & 1u);
    return (ushort)(r >> 16);
}
__device__ __forceinline__ float bf2f(ushort u) {
    return __uint_as_float(((unsigned int)u) << 16);
}
// fast tanh: (e^2x - 1)/(e^2x + 1); err ~1e-6 << bf16 ulp
__device__ __forceinline__ float tanh_fast(float x) {
    float xc = fminf(fmaxf(x, -15.0f), 15.0f);
    float e = __expf(2.0f * xc);
    return (e - 1.0f) * __builtin_amdgcn_rcpf(e + 1.0f);
}

// ---------------------------------------------------------------------------
// bf16 MFMA GEMM, tile 64x64, BK=64 (two MFMA k-steps per staged tile),
// 256 threads = 4 waves (2x2 grid, each wave 32x32).  Ping-pong LDS, ONE
// barrier per BK-64 iter; all 8 fragment ds_reads issue up front so ks=0
// MFMAs run under the ks=1 read latency.  K-loop fully unrolled (KK param).
// 32KB LDS => 5 blocks/CU.  [Round-9 config: measured best, 238.4 us total.]
// XOR chunk swizzle slot(row,c) = c ^ ((row>>1)&7): ds_read_b128 2-way = free.
// XCD band swizzle: band g&7 owns a contiguous M strip (A stays in its L2).
// Epilogues:
//  EPI 0: fp32 store acc + bias[c]                      -> (float*)Cout, ldc
//  EPI 1: bf16 store tanh_fast(acc + bias[c])           -> (ushort*)Cout, ldc
//  EPI 2: u = relu((acc + 2*bias[c]) * rcp(denom[r]));
//         if Cout: bf16 store u; if gout: gout[r*512+xoff+c]=bf16(u+xgb[...])
//  EPI 3: s_arr[r] += sum_c acc[r][c] * tcb[r*tcld+c]   (no store)
// ---------------------------------------------------------------------------
template <int TM, int TN, int KK, int EPI>
__global__ __launch_bounds__(256) void gemm_lds(
    const ushort* __restrict__ A, int lda,
    const ushort* __restrict__ Bt, int N,
    const float* __restrict__ bias,
    const float* __restrict__ denom,
    const ushort* __restrict__ tcb, int tcld,
    float* __restrict__ s_arr,
    void* __restrict__ Cout, int ldc,
    const ushort* __restrict__ xgb, int xoff, ushort* __restrict__ gout)
{
    constexpr int MI = TM / 32;                 // mfma m-tiles per wave
    constexpr int NI = TN / 32;                 // mfma n-tiles per wave
    constexpr int ROWS = TM + TN;               // staged rows per iter
    constexpr int CPT = (ROWS * 8) / 256;       // 16B chunks per thread (BK=64)
    constexpr int MT = 16384 / TM;
    constexpr int MT_PER_BAND = MT / 8;
    constexpr int NK = KK >> 6;                 // BK = 64
    __shared__ ushort S[2 * ROWS * 64];

    const int g = blockIdx.x;
    const int band = g & 7, within = g >> 3;
    const int nt = within / MT_PER_BAND;
    const int mt = band * MT_PER_BAND + (within - nt * MT_PER_BAND);
    const int m0 = mt * TM, n0 = nt * TN;
    const int w = threadIdx.x >> 6, L = threadIdx.x & 63;
    const int wr0 = (w >> 1) * (TM / 2), wc0 = (w & 1) * (TN / 2);
    const int lrow = L & 15, quad = L >> 4;

    // per-thread staging base pointers (computed once; loop adds imm offsets)
    const ushort* gbase[CPT];
#pragma unroll
    for (int rr = 0; rr < CPT; ++rr) {
        const int chunk = rr * 256 + (w << 6) + L;
        const int row = chunk >> 3, slot = chunk & 7;
        const int ca = slot ^ ((row >> 1) & 7);              // swizzled source
        gbase[rr] = (row < TM)
            ? A  + (size_t)(m0 + row) * lda    + (ca << 3)
            : Bt + (size_t)(n0 + row - TM) * KK + (ca << 3);
    }

    floatx4 zero4 = {0.0f, 0.0f, 0.0f, 0.0f};
    floatx4 acc[MI][NI];
#pragma unroll
    for (int i = 0; i < MI; ++i)
#pragma unroll
        for (int j = 0; j < NI; ++j) acc[i][j] = zero4;

    auto stage = [&](int buf, int k0) {
        ushort* Sd = S + buf * (ROWS * 64);
#pragma unroll
        for (int rr = 0; rr < CPT; ++rr) {
            __builtin_amdgcn_global_load_lds(
                (const __attribute__((address_space(1))) unsigned int*)(gbase[rr] + k0),
                (__attribute__((address_space(3))) unsigned int*)(Sd + (rr * 256 + (w << 6)) * 8),
                16, 0, 0);
        }
    };

    stage(0, 0);                                  // preload tile 0
#pragma unroll
    for (int kk = 0; kk < NK; ++kk) {
        __syncthreads();                          // tile kk landed
        if (kk + 1 < NK) stage((kk + 1) & 1, (kk + 1) << 6);  // compile-time guard

        const ushort* Sc = S + (kk & 1) * (ROWS * 64);
        short8 af[2][MI], bfr[2][NI];
#pragma unroll
        for (int ks = 0; ks < 2; ++ks) {
#pragma unroll
            for (int mi = 0; mi < MI; ++mi) {
                const int row = wr0 + (mi << 4) + lrow;
                const int slot = ((ks << 2) + quad) ^ ((row >> 1) & 7);
                af[ks][mi] = *(const short8*)(Sc + row * 64 + (slot << 3));
            }
#pragma unroll
            for (int ni = 0; ni < NI; ++ni) {
                const int row = TM + wc0 + (ni << 4) + lrow;
                const int slot = ((ks << 2) + quad) ^ ((row >> 1) & 7);
                bfr[ks][ni] = *(const short8*)(Sc + row * 64 + (slot << 3));
            }
        }
#pragma unroll
        for (int ks = 0; ks < 2; ++ks)
#pragma unroll
            for (int mi = 0; mi < MI; ++mi)
#pragma unroll
                for (int ni = 0; ni < NI; ++ni)
                    acc[mi][ni] = __builtin_amdgcn_mfma_f32_16x16x32_bf16(
                        af[ks][mi], bfr[ks][ni], acc[mi][ni], 0, 0, 0);
    }

    // C/D layout (m89-verified): col = lane&15, row = (lane>>4)*4 + reg.
    if constexpr (EPI == 3) {
#pragma unroll
        for (int mi = 0; mi < MI; ++mi) {
            float rs[4] = {0.f, 0.f, 0.f, 0.f};
#pragma unroll
            for (int ni = 0; ni < NI; ++ni) {
                const int gc = n0 + wc0 + (ni << 4) + lrow;
#pragma unroll
                for (int p = 0; p < 4; ++p) {
                    const int gr = m0 + wr0 + (mi << 4) + (quad << 2) + p;
                    rs[p] += acc[mi][ni][p] * bf2f(tcb[(size_t)gr * tcld + gc]);
                }
            }
#pragma unroll
            for (int p = 0; p < 4; ++p)
#pragma unroll
                for (int o = 1; o < 16; o <<= 1) rs[p] += __shfl_xor(rs[p], o);
            if (lrow == 0) {
#pragma unroll
                for (int p = 0; p < 4; ++p)
                    atomicAdd(s_arr + m0 + wr0 + (mi << 4) + (quad << 2) + p, rs[p]);
            }
        }
    } else {
#pragma unroll
        for (int mi = 0; mi < MI; ++mi) {
#pragma unroll
            for (int p = 0; p < 4; ++p) {
                const int gr = m0 + wr0 + (mi << 4) + (quad << 2) + p;
                const float rdv = (EPI == 2) ? __builtin_amdgcn_rcpf(denom[gr]) : 1.0f;
#pragma unroll
                for (int ni = 0; ni < NI; ++ni) {
                    const int gc = n0 + wc0 + (ni << 4) + lrow;
                    const float v = acc[mi][ni][p];
                    if constexpr (EPI == 0) {
                        ((float*)Cout)[(size_t)gr * ldc + gc] = v + bias[gc];
                    } else if constexpr (EPI == 1) {
                        ((ushort*)Cout)[(size_t)gr * ldc + gc] = f2bf(tanh_fast(v + bias[gc]));
                    } else {
                        float u = (v + 2.0f * bias[gc]) * rdv;
                        u = u > 0.0f ? u : 0.0f;
                        if (Cout)
                            ((ushort*)Cout)[(size_t)gr * ldc + gc] = f2bf(u);
                        if (gout)
                            gout[(size_t)gr * 512 + xoff + gc] =
                                f2bf(u + bf2f(xgb[(size_t)gr * 512 + xoff + gc]));
                    }
                }
            }
        }
    }
}

// ---------------------------------------------------------------------------
// Prep: blocks [0,4096): xb = bf16(x) + fdot[r] = x[r].fiw  (one wave/row)
//       blocks [4096,5440): weight transposes fp32[K][N] -> bf16[N][K]
//       block 5440: bias concat
//       blocks [5441,5457): zero the stats region (replaces hipMemsetAsync)
// ---------------------------------------------------------------------------
__global__ __launch_bounds__(256) void prep_k(
    const float* __restrict__ x, const float* __restrict__ fiw,
    ushort* __restrict__ xb, float* __restrict__ fdot,
    const float* __restrict__ tp_w, const float* __restrict__ tc_w,
    const float* __restrict__ bilw, const float* __restrict__ ow,
    const float* __restrict__ w0, const float* __restrict__ w1,
    const float* __restrict__ tp_b, const float* __restrict__ tc_b,
    ushort* __restrict__ tptcwT, ushort* __restrict__ bilwT,
    ushort* __restrict__ owT, ushort* __restrict__ w0T,
    ushort* __restrict__ w1T, float* __restrict__ bias2,
    float* __restrict__ zstats, int zcount)
{
    const int blk0 = blockIdx.x;
    if (blk0 < 4096) {
        const int wv = threadIdx.x >> 6, L = threadIdx.x & 63;
        const int r = (blk0 << 2) + wv;
        const float* xr = x + (size_t)r * DD;
        const int c0 = L << 3;
        float4 v0 = *(const float4*)(xr + c0);
        float4 v1 = *(const float4*)(xr + c0 + 4);
        float4 f0 = *(const float4*)(fiw + c0);
        float4 f1 = *(const float4*)(fiw + c0 + 4);
        float d = v0.x * f0.x + v0.y * f0.y + v0.z * f0.z + v0.w * f0.w
                + v1.x * f1.x + v1.y * f1.y + v1.z * f1.z + v1.w * f1.w;
        ushort8v o;
        o[0] = f2bf(v0.x); o[1] = f2bf(v0.y); o[2] = f2bf(v0.z); o[3] = f2bf(v0.w);
        o[4] = f2bf(v1.x); o[5] = f2bf(v1.y); o[6] = f2bf(v1.z); o[7] = f2bf(v1.w);
        *(ushort8v*)(xb + (size_t)r * DD + c0) = o;
#pragma unroll
        for (int off = 32; off > 0; off >>= 1) d += __shfl_xor(d, off);
        if (L == 0) fdot[r] = d;
        return;
    }
    if (blk0 >= 5441) {                       // zero stats region
        for (int i = (blk0 - 5441) * 256 + threadIdx.x; i < zcount; i += 16 * 256)
            zstats[i] = 0.0f;
        return;
    }
    const int blk = blk0 - 4096;
    if (blk >= 1344) {
        for (int i = threadIdx.x; i < 512; i += 256) {
            bias2[i] = tp_b[i];
            bias2[512 + i] = tc_b[i];
        }
        return;
    }
    const float* W; ushort* Wt; int K, N, local;
    if (blk < 256)       { W = tp_w; Wt = tptcwT;              K = 512; N = 512; local = blk; }
    else if (blk < 512)  { W = tc_w; Wt = tptcwT + 512 * 512;  K = 512; N = 512; local = blk - 256; }
    else if (blk < 768)  { W = bilw; Wt = bilwT;               K = 512; N = 512; local = blk - 512; }
    else if (blk < 1024) { W = ow;   Wt = owT;                 K = 512; N = 512; local = blk - 768; }
    else if (blk < 1152) { W = w0;   Wt = w0T;                 K = 512; N = 256; local = blk - 1024; }
    else                 { W = w1;   Wt = w1T;                 K = 768; N = 256; local = blk - 1152; }

    __shared__ float t[32][33];
    const int nb = N >> 5;
    const int kb = local / nb, nbb = local % nb;
    const int k0 = kb << 5, n0 = nbb << 5;
    const int c = threadIdx.x & 31, r = threadIdx.x >> 5;   // r 0..7
#pragma unroll
    for (int i = 0; i < 4; ++i)
        t[r + 8 * i][c] = W[(size_t)(k0 + r + 8 * i) * N + n0 + c];
    __syncthreads();
#pragma unroll
    for (int i = 0; i < 4; ++i)
        Wt[(size_t)(n0 + r + 8 * i) * K + k0 + c] = f2bf(t[c][r + 8 * i]);
}

// ---------------------------------------------------------------------------
// Per batch (block = 1024 threads = 1 batch): a=exp(s), f=exp(fdot),
// S=sum a, H=sum a*f (tree reduce, no atomics), denom = 2 - a*f/H.
// ---------------------------------------------------------------------------
__global__ __launch_bounds__(1024) void finalize_k(
    const float* __restrict__ s_arr, const float* __restrict__ fdot,
    float* __restrict__ a, float* __restrict__ f,
    float* __restrict__ Sb, float* __restrict__ Hb, float* __restrict__ den)
{
    __shared__ float redS[16], redH[16];
    __shared__ float Hsh;
    const int b = blockIdx.x, t = threadIdx.x;
    const int r = (b << 10) + t;
    const float av = __expf(s_arr[r]), fv = __expf(fdot[r]);
    a[r] = av; f[r] = fv;
    float s1 = av, s2 = av * fv;
#pragma unroll
    for (int o = 32; o > 0; o >>= 1) { s1 += __shfl_xor(s1, o); s2 += __shfl_xor(s2, o); }
    if ((t & 63) == 0) { redS[t >> 6] = s1; redH[t >> 6] = s2; }
    __syncthreads();
    if (t == 0) {
        float S = 0.f, H = 0.f;
        for (int i = 0; i < 16; ++i) { S += redS[i]; H += redH[i]; }
        Sb[b] = S; Hb[b] = H; Hsh = H;
    }
    __syncthreads();
    den[r] = 2.0f - av * fv * __builtin_amdgcn_rcpf(Hsh);
}

// ---------------------------------------------------------------------------
// Per batch: P[c] = sum_n a_n V[n,c]; Q[c] = sum_n a_n f_n V[n,c].  V is bf16.
// grid = 16 batches x 16 row-chunks(64); LDS-reduce then <=16-collider atomics.
// ---------------------------------------------------------------------------
__global__ __launch_bounds__(256) void batch_pq(
    const ushort* __restrict__ V, const float* __restrict__ a, const float* __restrict__ f,
    float* __restrict__ P, float* __restrict__ Q, int C)
{
    __shared__ float redP[256][4];
    __shared__ float redQ[256][4];
    const int b = blockIdx.x >> 4;
    const int chunk = blockIdx.x & 15;
    const int c4cnt = C >> 2;
    const int rg = 256 / c4cnt;
    const int c4 = threadIdx.x & (c4cnt - 1);
    const int sub = threadIdx.x / c4cnt;
    const ushort* Vb = V + (size_t)b * 1024 * C;
    const float* ab = a + (b << 10);
    const float* fb = f + (b << 10);
    const int n0 = chunk << 6;
    float4 p = {0, 0, 0, 0}, q = {0, 0, 0, 0};
    for (int n = n0 + sub; n < n0 + 64; n += rg) {
        const float av = ab[n], afv = av * fb[n];
        ushort4v u = *(const ushort4v*)(Vb + (size_t)n * C + (c4 << 2));
        float4 v = {bf2f(u[0]), bf2f(u[1]), bf2f(u[2]), bf2f(u[3])};
        p.x += av * v.x; p.y += av * v.y; p.z += av * v.z; p.w += av * v.w;
        q.x += afv * v.x; q.y += afv * v.y; q.z += afv * v.z; q.w += afv * v.w;
    }
    redP[threadIdx.x][0] = p.x; redP[threadIdx.x][1] = p.y;
    redP[threadIdx.x][2] = p.z; redP[threadIdx.x][3] = p.w;
    redQ[threadIdx.x][0] = q.x; redQ[threadIdx.x][1] = q.y;
    redQ[threadIdx.x][2] = q.z; redQ[threadIdx.x][3] = q.w;
    __syncthreads();
    if (sub == 0) {
        for (int s = 1; s < rg; ++s) {
            const int t2 = threadIdx.x + s * c4cnt;
            p.x += redP[t2][0]; p.y += redP[t2][1]; p.z += redP[t2][2]; p.w += redP[t2][3];
            q.x += redQ[t2][0]; q.y += redQ[t2][1]; q.z += redQ[t2][2]; q.w += redQ[t2][3];
        }
        float* Pp = P + b * C + (c4 << 2);
        float* Qp = Q + b * C + (c4 << 2);
        atomicAdd(Pp + 0, p.x); atomicAdd(Pp + 1, p.y);
        atomicAdd(Pp + 2, p.z); atomicAdd(Pp + 3, p.w);
        atomicAdd(Qp + 0, q.x); atomicAdd(Qp + 1, q.y);
        atomicAdd(Qp + 2, q.z); atomicAdd(Qp + 3, q.w);
    }
}

// ---------------------------------------------------------------------------
// h = adj@V + V (rank-3 + diagonal closed form), V bf16, bf16 store to
// outb[r][co..co+C) with row stride ldo.
// ---------------------------------------------------------------------------
__global__ __launch_bounds__(256) void mix_k(
    const ushort* __restrict__ V, const float* __restrict__ P, const float* __restrict__ Q,
    const float* __restrict__ a, const float* __restrict__ f,
    const float* __restrict__ Sb, const float* __restrict__ Hb,
    ushort* __restrict__ outb, int C, int ldo, int co)
{
    const int idx = blockIdx.x * 256 + threadIdx.x;
    const int c4c = C >> 2;
    const int r = idx / c4c, c4 = idx - r * c4c;
    const int b = r >> 10;
    const float av = a[r], fv = f[r], S = Sb[b], H = Hb[b];
    const float rS = __builtin_amdgcn_rcpf(S);
    const float beta = av * rS * __builtin_amdgcn_rcpf(H);
    const float alpha = 1.0f - av * rS;
    const float cp = rS - beta * fv;
    ushort4v u = *(const ushort4v*)(V + (size_t)r * C + (c4 << 2));
    float4 v = {bf2f(u[0]), bf2f(u[1]), bf2f(u[2]), bf2f(u[3])};
    const float* Pp = P + b * C + (c4 << 2);
    const float* Qp = Q + b * C + (c4 << 2);
    ushort4v o;
    o[0] = f2bf(alpha * v.x + cp * Pp[0] + beta * Qp[0]);
    o[1] = f2bf(alpha * v.y + cp * Pp[1] + beta * Qp[1]);
    o[2] = f2bf(alpha * v.z + cp * Pp[2] + beta * Qp[2]);
    o[3] = f2bf(alpha * v.w + cp * Pp[3] + beta * Qp[3]);
    *(ushort4v*)(outb + (size_t)r * ldo + co + (c4 << 2)) = o;
}

extern "C" void kernel_launch(void* const* d_in, const int* in_sizes, int n_in,
                              void* d_out, int out_size, void* d_ws, size_t ws_size,
                              hipStream_t stream)
{
    (void)in_sizes; (void)n_in; (void)out_size; (void)ws_size;
    const float* x    = (const float*)d_in[0];
    const float* tp_w = (const float*)d_in[1];
    const float* tp_b = (const float*)d_in[2];
    const float* tc_w = (const float*)d_in[3];
    const float* tc_b = (const float*)d_in[4];
    const float* fi_w = (const float*)d_in[5];
    const float* bilw = (const float*)d_in[6];
    const float* w0   = (const float*)d_in[7];
    const float* b0   = (const float*)d_in[8];
    const float* w1   = (const float*)d_in[9];
    const float* b1   = (const float*)d_in[10];
    const float* ow   = (const float*)d_in[11];
    const float* ob   = (const float*)d_in[12];

    char* W = (char*)d_ws;
    ushort* xb    = (ushort*)W;                          // [0,16M)  xb -> gcnb (elem-wise overwrite)
    ushort* gcnb  = xb;
    ushort* tptcb = (ushort*)(W + ((size_t)16 << 20));   // [16M,48M) 32MB; dies after s-GEMM
    ushort* Hbuf  = tptcb;                               // [16M,40M) 24MB overlay: [h0|hg] ld 768
    ushort* g0b   = (ushort*)(W + ((size_t)48 << 20));   // 8MB
    ushort* tptcwT= (ushort*)(W + ((size_t)56 << 20));   // 1024x512
    ushort* bilwT = tptcwT + 524288;                     // 512x512
    ushort* owT   = bilwT + 262144;                      // 512x512
    ushort* w0T   = owT + 262144;                        // 256x512
    ushort* w1T   = w0T + 131072;                        // 256x768
    float*  bias2 = (float*)(w1T + 196608);              // 1024
    float* stats  = (float*)(W + ((size_t)60 << 20));
    // contiguous zero region (zeroed by prep_k): s_arr..Q1 = 40960 floats
    float* s_arr  = stats;             // 16384
    float* P0     = s_arr + 16384;     // 8192
    float* Q0     = P0 + 8192;         // 8192
    float* P1     = Q0 + 8192;         // 4096
    float* Q1     = P1 + 4096;         // 4096
    const int zcount = 16384 + 2 * 8192 + 2 * 4096;
    float* fdot   = Q1 + 4096;
    float* arr_a  = fdot + BN;
    float* arr_f  = arr_a + BN;
    float* arr_den= arr_f + BN;
    float* Sb     = arr_den + BN;
    float* Hb     = Sb + 16;

    // prep: xb=bf16(x), fdot, weight transposes, bias concat, stats zeroing
    prep_k<<<5457, 256, 0, stream>>>(x, fi_w, xb, fdot, tp_w, tc_w, bilw, ow, w0, w1,
                                     tp_b, tc_b, tptcwT, bilwT, owT, w0T, w1T, bias2,
                                     s_arr, zcount);
    // [tp|tc] = tanh(x@[tpw|tcw] + [tpb|tcb])  (one N=1024 GEMM, bf16 out)
    gemm_lds<64, 64, 512, 1><<<4096, 256, 0, stream>>>(xb, 512, tptcwT, 1024, bias2,
        nullptr, nullptr, 0, nullptr, tptcb, 1024, nullptr, 0, nullptr);
    // s[r] = (tp@bilw)[r] . tc[r]   (U never materialized)
    gemm_lds<64, 64, 512, 3><<<2048, 256, 0, stream>>>(tptcb, 1024, bilwT, 512, nullptr,
        nullptr, tptcb + 512, 1024, s_arr, nullptr, 0, nullptr, 0, nullptr);
    // a, f, S, H, denom
    finalize_k<<<16, 1024, 0, stream>>>(s_arr, fdot, arr_a, arr_f, Sb, Hb, arr_den);
    // layer 0: h0 = adj@x + x -> Hbuf[:, 0:512] bf16  (x read as bf16 xb)
    batch_pq<<<256, 256, 0, stream>>>(xb, arr_a, arr_f, P0, Q0, 512);
    mix_k<<<8192, 256, 0, stream>>>(xb, P0, Q0, arr_a, arr_f, Sb, Hb, Hbuf, 512, 768, 0);
    // g0 = relu((h0@W0 + 2 b0)/den): store g0b bf16 AND gcn[:,0:256]=bf16(g0+x)
    gemm_lds<64, 64, 512, 2><<<1024, 256, 0, stream>>>(Hbuf, 768, w0T, 256, b0,
        arr_den, nullptr, 0, nullptr, g0b, 256, xb, 0, gcnb);
    // layer 1: hg = adj@g0 + g0 -> Hbuf[:, 512:768] bf16
    batch_pq<<<256, 256, 0, stream>>>(g0b, arr_a, arr_f, P1, Q1, 256);
    mix_k<<<4096, 256, 0, stream>>>(g0b, P1, Q1, arr_a, arr_f, Sb, Hb, Hbuf, 256, 768, 512);
    // g1 = relu(([h0|hg]@W1 + 2 b1)/den): gcn[:,256:512]=bf16(g1+x) (no g1 buf)
    gemm_lds<64, 64, 768, 2><<<1024, 256, 0, stream>>>(Hbuf, 768, w1T, 256, b1,
        arr_den, nullptr, 0, nullptr, nullptr, 0, xb, 256, gcnb);
    // out = gcn@out_w + out_b  (fp32)
    gemm_lds<64, 64, 512, 0><<<2048, 256, 0, stream>>>(gcnb, 512, owT, 512, ob,
        nullptr, nullptr, 0, nullptr, (float*)d_out, 512, nullptr, 0, nullptr);
}